// Round 9
// baseline (9132.583 us; speedup 1.0000x reference)
//
#include <hip/hip_runtime.h>
#include <hip/hip_bf16.h>

// LSTM (B=64,T=512,I=512,H=1024,O=1), 2 layers + sigmoid head.
// R9 = R8 + wave specialization: the input GEMM moves OFF the critical path.
//  - 256 WGs x 512 thr (8 waves). Waves 0-3 = recurrent (global barrier,
//    hh GEMM, elementwise, h store). Waves 4-7 = input producers: compute
//    gx[t] = x[t] @ W_in^T into a 2-slot LDS ring, throttled by workgroup
//    LDS seq counters only -- they never touch the global barrier.
//  - Recurrent waves seed the hh-MFMA accumulator from the gx slot.
//  - Intra-WG arrive: each rec wave drains own stores (vmcnt(0)) -> LDS
//    counter; wave0 alone does the global RELAXED RMW (no wbl2 -- R8's win).
//  - h protocol unchanged from R8: sc0sc1 u64 write-through stores, plain
//    cached reads of per-step FRESH slabs in REVERSE address order.

namespace {

constexpr int B_ = 64, T_ = 512, I_ = 512, H_ = 1024;
constexpr int NWG = 256, NTHR = 512;
constexpr int BH = B_ * H_;

typedef __attribute__((ext_vector_type(8))) short short8;
typedef __attribute__((ext_vector_type(4))) float f32x4;

#define MFMA16(a, b, c) __builtin_amdgcn_mfma_f32_16x16x32_bf16((a), (b), (c), 0, 0, 0)

__device__ __forceinline__ float sigm(float x)  { return 1.f / (1.f + __expf(-x)); }
__device__ __forceinline__ float tanhx(float x) { return 2.f / (1.f + __expf(-2.f * x)) - 1.f; }

__device__ __forceinline__ unsigned f2bf(float f) {
  unsigned u = __float_as_uint(f);
  unsigned rnd = 0x7FFFu + ((u >> 16) & 1u);
  return (u + rnd) >> 16;   // low 16 bits valid
}
__device__ __forceinline__ float bf2f(unsigned short s) {
  return __uint_as_float(((unsigned)s) << 16);
}

__global__ void cvt_bf16_k(const float* __restrict__ src, unsigned short* __restrict__ dst, int n4) {
  int i = blockIdx.x * 256 + threadIdx.x;
  if (i >= n4) return;
  float4 v = reinterpret_cast<const float4*>(src)[i];
  ushort4 o;
  o.x = (unsigned short)f2bf(v.x); o.y = (unsigned short)f2bf(v.y);
  o.z = (unsigned short)f2bf(v.z); o.w = (unsigned short)f2bf(v.w);
  reinterpret_cast<ushort4*>(dst)[i] = o;
}

// zero slab-0 of both records (at REVERSED position T_) and all barrier lines
__global__ void zero_init_k(unsigned short* __restrict__ h1, unsigned short* __restrict__ h2,
                            unsigned* __restrict__ bar) {
  int i = blockIdx.x * 256 + threadIdx.x;
  if (i < BH) h1[(size_t)T_ * BH + i] = 0;
  if (i < BH) h2[(size_t)T_ * BH + i] = 0;
  if (i < 4096) bar[i] = 0;             // 16KB barrier region (both layers)
}

// bars per layer: 32 group lines (8 WGs each), counter g at bars[g*32].
// Monotonic: after all arrivals of step t each counter == 8*(t+1).
// h record (FRESH): slab s at hrec + (T_-s)*BH (reverse order).
template<int K_IN>
__global__ __launch_bounds__(NTHR, 2) void lstm_layer(
    const unsigned short* __restrict__ in, long long in_stride_t, long long in_stride_b,
    const unsigned short* __restrict__ w_in,   // [4H][K_IN] bf16
    const unsigned short* __restrict__ w_hh,   // [4H][H] bf16
    const float* __restrict__ b_ih, const float* __restrict__ b_hh,
    unsigned short* __restrict__ hrec,
    unsigned* __restrict__ bars)
{
  __shared__ unsigned short s_win[16 * K_IN];
  __shared__ unsigned short s_whh[16 * H_];
  __shared__ float gx[2][4][16][17];   // [slot][batch-tile][m][n], padded
  __shared__ unsigned prod_seq[2];     // input waves: 4 adds per produced gen
  __shared__ unsigned cons_seq[2];     // rec waves:   4 adds per consumed gen
  __shared__ unsigned rec_cnt;         // rec waves:   4 adds per step
  __shared__ int rel_flag;

  const int tid  = threadIdx.x;
  const int wg   = blockIdx.x;      // 0..255
  const int wave = tid >> 6;        // 0..7
  const int lane = tid & 63;
  const int bt   = wave & 3;        // batch tile (both roles)
  const int j0   = wg * 4;          // first hidden unit owned by this WG
  const int n    = lane & 15;       // gate-row (D column)
  const int k0   = (lane >> 4) * 8; // k offset within 32-wide K tile
  const int arow = bt * 16 + n;     // batch row (A fragment)
  const int swz_n = (n & 7) << 3;

  unsigned* grp = bars + (wg >> 3) * 32;   // 32 groups of 8 WGs

  if (tid == 0) {
    prod_seq[0] = 0; prod_seq[1] = 0;
    cons_seq[0] = 0; cons_seq[1] = 0;
    rec_cnt = 0; rel_flag = 0;
  }

  // ---- stage W slices into LDS with XOR swizzle (shorts: k ^= (r&7)<<3) ----
  constexpr int CH_IN = K_IN / 8;
  for (int c = tid; c < 16 * CH_IN; c += NTHR) {
    int r = c / CH_IN;
    int kc = (c % CH_IN) * 8;
    int grow = (r >> 2) * H_ + j0 + (r & 3);
    *reinterpret_cast<short8*>(&s_win[r * K_IN + (kc ^ ((r & 7) << 3))]) =
        *reinterpret_cast<const short8*>(&w_in[(size_t)grow * K_IN + kc]);
  }
  constexpr int CH_HH = H_ / 8;
  for (int c = tid; c < 16 * CH_HH; c += NTHR) {
    int r = c / CH_HH;
    int kc = (c % CH_HH) * 8;
    int grow = (r >> 2) * H_ + j0 + (r & 3);
    *reinterpret_cast<short8*>(&s_whh[r * H_ + (kc ^ ((r & 7) << 3))]) =
        *reinterpret_cast<const short8*>(&w_hh[(size_t)grow * H_ + kc]);
  }
  __syncthreads();   // staging + counter init visible; waves diverge after this

  if (wave >= 4) {
    // ================= INPUT PRODUCER WAVES (4..7) =================
    const unsigned short* a_in_base = in + (long long)arow * in_stride_b + k0;
    for (int t = 0; t < T_; ++t) {
      const int slot = t & 1;
      const unsigned gen = (unsigned)(t >> 1);
      // wait until slot's previous occupant (step t-2) fully consumed
      while (__hip_atomic_load(&cons_seq[slot], __ATOMIC_ACQUIRE, __HIP_MEMORY_SCOPE_WORKGROUP)
             < 4u * gen)
        __builtin_amdgcn_s_sleep(1);

      f32x4 a = {0.f, 0.f, 0.f, 0.f};
      const unsigned short* a_in = a_in_base + (long long)t * in_stride_t;
      #pragma unroll 8
      for (int kk = 0; kk < K_IN / 32; ++kk)
        a = MFMA16(*reinterpret_cast<const short8*>(a_in + kk * 32),
                   *reinterpret_cast<const short8*>(&s_win[n * K_IN + ((k0 + kk * 32) ^ swz_n)]),
                   a);
      #pragma unroll
      for (int r = 0; r < 4; ++r)
        gx[slot][bt][(lane >> 4) * 4 + r][n] = a[r];
      // publish (RELEASE forces lgkmcnt(0) -> gx writes complete first)
      if (lane == 0)
        __hip_atomic_fetch_add(&prod_seq[slot], 1u, __ATOMIC_RELEASE, __HIP_MEMORY_SCOPE_WORKGROUP);
    }
    return;
  }

  // ================= RECURRENT WAVES (0..3) =================
  const int grow_n = (n >> 2) * H_ + j0 + (n & 3);
  const float bias_n = b_ih[grow_n] + b_hh[grow_n];
  const int eb = bt * 16 + (lane >> 2); // batch 0..63 for elementwise
  const int eu = lane & 3;              // unit 0..3
  float cst = 0.f;

  for (int t = 0; t < T_; ++t) {
    const int slot = t & 1;
    const unsigned gen = (unsigned)(t >> 1);

    // ---- global wait for h[t] ----
    if (t > 0) {
      if (wave == 0) {
        const unsigned tgt = (unsigned)t * 8u;
        for (;;) {
          unsigned v = 0xFFFFFFFFu;
          if (lane < 32)
            v = __hip_atomic_load(bars + lane * 32, __ATOMIC_RELAXED, __HIP_MEMORY_SCOPE_AGENT);
          if (__all((int)(lane >= 32 || v >= tgt))) break;
          __builtin_amdgcn_s_sleep(1);
        }
        __builtin_amdgcn_fence(__ATOMIC_ACQUIRE, "workgroup");  // order h loads, no cache ops
        if (lane == 0)
          __hip_atomic_store(&rel_flag, t, __ATOMIC_RELEASE, __HIP_MEMORY_SCOPE_WORKGROUP);
      } else {
        while (__hip_atomic_load(&rel_flag, __ATOMIC_ACQUIRE, __HIP_MEMORY_SCOPE_WORKGROUP) < t)
          __builtin_amdgcn_s_sleep(1);
      }
    }

    // ---- wait for gx[t], seed accumulator from it ----
    while (__hip_atomic_load(&prod_seq[slot], __ATOMIC_ACQUIRE, __HIP_MEMORY_SCOPE_WORKGROUP)
           < 4u * (gen + 1))
      __builtin_amdgcn_s_sleep(1);
    f32x4 acc;
    acc[0] = gx[slot][bt][(lane >> 4) * 4 + 0][n];
    acc[1] = gx[slot][bt][(lane >> 4) * 4 + 1][n];
    acc[2] = gx[slot][bt][(lane >> 4) * 4 + 2][n];
    acc[3] = gx[slot][bt][(lane >> 4) * 4 + 3][n];
    // release the slot (RELEASE forces lgkmcnt(0) -> gx reads retired)
    if (lane == 0)
      __hip_atomic_fetch_add(&cons_seq[slot], 1u, __ATOMIC_RELEASE, __HIP_MEMORY_SCOPE_WORKGROUP);

    // ---- recurrent GEMM: h[slab t] @ W_hh^T (plain cached loads) ----
    const unsigned short* a_h = hrec + (size_t)(T_ - t) * BH + (size_t)arow * H_ + k0;
    #pragma unroll 8
    for (int kk = 0; kk < H_ / 32; ++kk) {
      short8 av = *reinterpret_cast<const short8*>(a_h + kk * 32);
      short8 bv = *reinterpret_cast<const short8*>(&s_whh[n * H_ + ((k0 + kk * 32) ^ swz_n)]);
      acc = MFMA16(av, bv, acc);
    }
    acc[0] += bias_n; acc[1] += bias_n; acc[2] += bias_n; acc[3] += bias_n;

    // ---- redistribute gates within the wave, elementwise ----
    const int rsel  = (lane >> 2) & 3;
    const int sbase = (lane & 48) | (lane & 3);
    float pg[4];
    #pragma unroll
    for (int g = 0; g < 4; ++g) {
      int src = sbase | (g << 2);
      float t0 = __shfl(acc[0], src, 64);
      float t1 = __shfl(acc[1], src, 64);
      float t2 = __shfl(acc[2], src, 64);
      float t3 = __shfl(acc[3], src, 64);
      pg[g] = (rsel == 0) ? t0 : (rsel == 1) ? t1 : (rsel == 2) ? t2 : t3;
    }
    float gi = sigm(pg[0]);
    float gf = sigm(pg[1]);
    float gg = tanhx(pg[2]);
    float go = sigm(pg[3]);
    cst = gf * cst + gi * gg;
    float hv = go * tanhx(cst);

    // pack 4 units for batch eb into one u64, write-through store to slab t+1
    unsigned hv16 = f2bf(hv) & 0xFFFFu;
    const int lb = lane & ~3;
    unsigned v1 = __shfl(hv16, lb | 1, 64);
    unsigned v2 = __shfl(hv16, lb | 2, 64);
    unsigned v3 = __shfl(hv16, lb | 3, 64);
    if (eu == 0) {
      unsigned long long qv = (unsigned long long)(hv16 | (v1 << 16)) |
                              ((unsigned long long)(v2 | (v3 << 16)) << 32);
      unsigned long long* dst = (unsigned long long*)
          (hrec + (size_t)(T_ - t - 1) * BH + (size_t)eb * H_ + j0);
      __hip_atomic_store(dst, qv, __ATOMIC_RELAXED, __HIP_MEMORY_SCOPE_AGENT);
    }

    // ---- arrive: drain own stores (ack'd at MALL), LDS count, wave0 RMWs ----
    asm volatile("s_waitcnt vmcnt(0)" ::: "memory");
    if (lane == 0)
      __hip_atomic_fetch_add(&rec_cnt, 1u, __ATOMIC_RELAXED, __HIP_MEMORY_SCOPE_WORKGROUP);
    if (wave == 0) {
      while (__hip_atomic_load(&rec_cnt, __ATOMIC_ACQUIRE, __HIP_MEMORY_SCOPE_WORKGROUP)
             < 4u * (unsigned)(t + 1))
        __builtin_amdgcn_s_sleep(1);
      if (lane == 0)
        __hip_atomic_fetch_add(grp, 1u, __ATOMIC_RELAXED, __HIP_MEMORY_SCOPE_AGENT);
    }
  }
}

__global__ void out_head(const unsigned short* __restrict__ h2,
                         const float* __restrict__ W_out,
                         const float* __restrict__ b_out,
                         float* __restrict__ out) {
  int b = blockIdx.x;      // 64
  int lane = threadIdx.x;  // 64 (one wave)
  float s = 0.f;
  for (int k = lane; k < H_; k += 64)
    s += bf2f(h2[(size_t)b * H_ + k]) * W_out[k];
  #pragma unroll
  for (int off = 32; off; off >>= 1) s += __shfl_down(s, off, 64);
  if (lane == 0) out[b] = sigm(s + b_out[0]);
}

} // namespace

extern "C" void kernel_launch(void* const* d_in, const int* in_sizes, int n_in,
                              void* d_out, int out_size, void* d_ws, size_t ws_size,
                              hipStream_t stream) {
  const float* x    = (const float*)d_in[0];
  const float* Wih0 = (const float*)d_in[1];
  const float* Whh0 = (const float*)d_in[2];
  const float* bih0 = (const float*)d_in[3];
  const float* bhh0 = (const float*)d_in[4];
  const float* Wih1 = (const float*)d_in[5];
  const float* Whh1 = (const float*)d_in[6];
  const float* bih1 = (const float*)d_in[7];
  const float* bhh1 = (const float*)d_in[8];
  const float* Wout = (const float*)d_in[9];
  const float* bout = (const float*)d_in[10];
  float* out = (float*)d_out;

  char* ws = (char*)d_ws;
  size_t off = 0;
  auto alloc = [&](size_t bytes) -> char* {
    char* p = ws + off;
    off += (bytes + 4095) & ~(size_t)4095;   // 4KB-align every region
    return p;
  };
  const size_t REC = (size_t)(T_ + 1) * BH * 2;       // 67.2 MB (513 slabs)

  unsigned* bar        = (unsigned*)alloc(16384);     // 4096 u32: L0 at 0, L1 at 2048
  unsigned short* xb   = (unsigned short*)alloc((size_t)B_ * T_ * I_ * 2);
  unsigned short* wih0 = (unsigned short*)alloc((size_t)4 * H_ * I_ * 2);
  unsigned short* whh0 = (unsigned short*)alloc((size_t)4 * H_ * H_ * 2);
  unsigned short* wih1 = (unsigned short*)alloc((size_t)4 * H_ * H_ * 2);
  unsigned short* whh1 = (unsigned short*)alloc((size_t)4 * H_ * H_ * 2);
  unsigned short* h1   = (unsigned short*)alloc(REC);
  unsigned short* h2   = (unsigned short*)alloc(REC);

  auto cvt = [&](const float* s, unsigned short* d, int nelem) {
    int n4 = nelem / 4;
    cvt_bf16_k<<<(n4 + 255) / 256, 256, 0, stream>>>(s, d, n4);
  };
  cvt(x,    xb,   B_ * T_ * I_);
  cvt(Wih0, wih0, 4 * H_ * I_);
  cvt(Whh0, whh0, 4 * H_ * H_);
  cvt(Wih1, wih1, 4 * H_ * H_);
  cvt(Whh1, whh1, 4 * H_ * H_);
  zero_init_k<<<(BH + 255) / 256, 256, 0, stream>>>(h1, h2, bar);

  // layer 0: xb [B][T][I] bf16 (stride_t=I, stride_b=T*I), fresh reversed record
  lstm_layer<I_><<<NWG, NTHR, 0, stream>>>(
      xb, (long long)I_, (long long)T_ * I_,
      wih0, whh0, bih0, bhh0, h1, bar);

  // layer 1: input h1 slabs s=1..512 at h1+(T_-s)*BH -> base h1+(T_-1)*BH,
  // stride_t = -BH; within-slab [b][k]: stride_b = H
  lstm_layer<H_><<<NWG, NTHR, 0, stream>>>(
      h1 + (size_t)(T_ - 1) * BH, -(long long)BH, (long long)H_,
      wih1, whh1, bih1, bhh1, h2, bar + 2048);

  // final h2 = slab T at reversed offset 0
  out_head<<<B_, 64, 0, stream>>>(h2, Wout, bout, out);
}

// Round 10
// 7583.371 us; speedup vs baseline: 1.2043x; 1.2043x over previous
//
#include <hip/hip_runtime.h>
#include <hip/hip_bf16.h>

// LSTM (B=64,T=512,I=512,H=1024,O=1), 2 layers + sigmoid head.
// R10 = R8 (specialization reverted) + two serial-path cuts:
//  1) Operand swap: A = W (LDS, unit-major rows), B = h/x (global). D then
//     lands as [W-row][batch]: lane holds all 4 gates (regs) of one unit
//     (lane>>4) for one batch (lane&15) -> elementwise needs ZERO shuffles
//     (was 16 shfls + select chains).
//  2) h-fragment prefetch: all 32 B-fragments loaded into regs before the
//     MFMA chain (one exposed MALL round trip instead of ~4).
//     __launch_bounds__(256,1) raises the VGPR cap to 256.
// Protocol unchanged from R8: sc0sc1 u64 write-through h stores, plain cached
// h reads of per-step FRESH slabs in REVERSE address order, 32-group RELAXED
// arrive (no wbl2), wave0 32-line poll + LDS rel_flag, workgroup acquire
// fence, input GEMM for t+1 in the post-arrive shadow.

namespace {

constexpr int B_ = 64, T_ = 512, I_ = 512, H_ = 1024;
constexpr int NWG = 256, NTHR = 256;
constexpr int BH = B_ * H_;

typedef __attribute__((ext_vector_type(8))) short short8;
typedef __attribute__((ext_vector_type(4))) float f32x4;

#define MFMA16(a, b, c) __builtin_amdgcn_mfma_f32_16x16x32_bf16((a), (b), (c), 0, 0, 0)

__device__ __forceinline__ float sigm(float x)  { return 1.f / (1.f + __expf(-x)); }
__device__ __forceinline__ float tanhx(float x) { return 2.f / (1.f + __expf(-2.f * x)) - 1.f; }

__device__ __forceinline__ unsigned f2bf(float f) {
  unsigned u = __float_as_uint(f);
  unsigned rnd = 0x7FFFu + ((u >> 16) & 1u);
  return (u + rnd) >> 16;   // low 16 bits valid
}
__device__ __forceinline__ float bf2f(unsigned short s) {
  return __uint_as_float(((unsigned)s) << 16);
}

__global__ void cvt_bf16_k(const float* __restrict__ src, unsigned short* __restrict__ dst, int n4) {
  int i = blockIdx.x * 256 + threadIdx.x;
  if (i >= n4) return;
  float4 v = reinterpret_cast<const float4*>(src)[i];
  ushort4 o;
  o.x = (unsigned short)f2bf(v.x); o.y = (unsigned short)f2bf(v.y);
  o.z = (unsigned short)f2bf(v.z); o.w = (unsigned short)f2bf(v.w);
  reinterpret_cast<ushort4*>(dst)[i] = o;
}

// zero slab-0 of both records (at REVERSED position T_) and all barrier lines
__global__ void zero_init_k(unsigned short* __restrict__ h1, unsigned short* __restrict__ h2,
                            unsigned* __restrict__ bar) {
  int i = blockIdx.x * 256 + threadIdx.x;
  if (i < BH) h1[(size_t)T_ * BH + i] = 0;
  if (i < BH) h2[(size_t)T_ * BH + i] = 0;
  if (i < 4096) bar[i] = 0;             // 16KB barrier region (both layers)
}

// bars per layer: 32 group lines (8 WGs each), counter g at bars[g*32].
// Monotonic: after all arrivals of step t each counter == 8*(t+1).
// h record (FRESH): slab s at hrec + (T_-s)*BH (reverse order).
template<int K_IN>
__global__ __launch_bounds__(NTHR, 1) void lstm_layer(
    const unsigned short* __restrict__ in, long long in_stride_t, long long in_stride_b,
    const unsigned short* __restrict__ w_in,   // [4H][K_IN] bf16
    const unsigned short* __restrict__ w_hh,   // [4H][H] bf16
    const float* __restrict__ b_ih, const float* __restrict__ b_hh,
    unsigned short* __restrict__ hrec,
    unsigned* __restrict__ bars)
{
  __shared__ unsigned short s_win[16 * K_IN];
  __shared__ unsigned short s_whh[16 * H_];
  __shared__ int rel_flag;

  const int tid  = threadIdx.x;
  const int wg   = blockIdx.x;      // 0..255
  const int wave = tid >> 6;        // 0..3 -> batch tile
  const int lane = tid & 63;
  const int j0   = wg * 4;          // first hidden unit owned by this WG
  const int n    = lane & 15;       // A row (unit-major W row) / B col (batch)
  const int u    = lane >> 4;       // unit this lane's D regs belong to
  const int k0   = (lane >> 4) * 8; // k offset within 32-wide K tile
  const int arow = wave * 16 + n;   // batch row for B fragments (h, x)
  const int swz_n = (n & 7) << 3;

  unsigned* grp = bars + (wg >> 3) * 32;   // 32 groups of 8 WGs

  if (tid == 0) rel_flag = 0;

  // ---- stage W slices into LDS, UNIT-MAJOR rows (r = u*4+g), XOR swizzle ----
  // slice row r -> global gate row (r&3)*H + j0 + (r>>2)
  constexpr int CH_IN = K_IN / 8;
  for (int c = tid; c < 16 * CH_IN; c += NTHR) {
    int r = c / CH_IN;
    int kc = (c % CH_IN) * 8;
    int grow = (r & 3) * H_ + j0 + (r >> 2);
    *reinterpret_cast<short8*>(&s_win[r * K_IN + (kc ^ ((r & 7) << 3))]) =
        *reinterpret_cast<const short8*>(&w_in[(size_t)grow * K_IN + kc]);
  }
  constexpr int CH_HH = H_ / 8;
  for (int c = tid; c < 16 * CH_HH; c += NTHR) {
    int r = c / CH_HH;
    int kc = (c % CH_HH) * 8;
    int grow = (r & 3) * H_ + j0 + (r >> 2);
    *reinterpret_cast<short8*>(&s_whh[r * H_ + (kc ^ ((r & 7) << 3))]) =
        *reinterpret_cast<const short8*>(&w_hh[(size_t)grow * H_ + kc]);
  }
  // bias per (gate g = reg, unit u = lane>>4)
  float bias_r[4];
  #pragma unroll
  for (int g = 0; g < 4; ++g)
    bias_r[g] = b_ih[g * H_ + j0 + u] + b_hh[g * H_ + j0 + u];
  __syncthreads();

  float cst = 0.f;   // c-state for (unit j0+u, batch wave*16+n)

  const unsigned short* a_in_base = in + (long long)arow * in_stride_b + k0;

  f32x4 acc = {0.f, 0.f, 0.f, 0.f};
  // prologue: input GEMM partial for t=0 (A = W_in from LDS, B = x)
  #pragma unroll 8
  for (int kk = 0; kk < K_IN / 32; ++kk)
    acc = MFMA16(*reinterpret_cast<const short8*>(&s_win[n * K_IN + ((k0 + kk * 32) ^ swz_n)]),
                 *reinterpret_cast<const short8*>(a_in_base + kk * 32),
                 acc);

  for (int t = 0; t < T_; ++t) {
    // ---- wait for h[t] (all WGs' step t-1 stores are at MALL) ----
    if (t > 0) {
      if (wave == 0) {
        const unsigned tgt = (unsigned)t * 8u;
        for (;;) {
          unsigned v = 0xFFFFFFFFu;
          if (lane < 32)
            v = __hip_atomic_load(bars + lane * 32, __ATOMIC_RELAXED, __HIP_MEMORY_SCOPE_AGENT);
          if (__all((int)(lane >= 32 || v >= tgt))) break;
          __builtin_amdgcn_s_sleep(1);
        }
        __builtin_amdgcn_fence(__ATOMIC_ACQUIRE, "workgroup");  // order h loads, no cache ops
        if (lane == 0)
          __hip_atomic_store(&rel_flag, t, __ATOMIC_RELEASE, __HIP_MEMORY_SCOPE_WORKGROUP);
      } else {
        while (__hip_atomic_load(&rel_flag, __ATOMIC_ACQUIRE, __HIP_MEMORY_SCOPE_WORKGROUP) < t)
          __builtin_amdgcn_s_sleep(1);
      }
    }

    // ---- recurrent GEMM: prefetch ALL h B-fragments, then MFMA chain ----
    const unsigned short* a_h = hrec + (size_t)(T_ - t) * BH + (size_t)arow * H_ + k0;
    short8 hf[H_ / 32];
    #pragma unroll
    for (int kk = 0; kk < H_ / 32; ++kk)
      hf[kk] = *reinterpret_cast<const short8*>(a_h + kk * 32);
    #pragma unroll
    for (int kk = 0; kk < H_ / 32; ++kk)
      acc = MFMA16(*reinterpret_cast<const short8*>(&s_whh[n * H_ + ((k0 + kk * 32) ^ swz_n)]),
                   hf[kk], acc);

    // ---- elementwise: lane already holds all 4 gates of (unit u, batch) ----
    float gi = sigm(acc[0] + bias_r[0]);
    float gf = sigm(acc[1] + bias_r[1]);
    float gg = tanhx(acc[2] + bias_r[2]);
    float go = sigm(acc[3] + bias_r[3]);
    cst = gf * cst + gi * gg;
    float hv = go * tanhx(cst);

    // pack 4 units for each batch into one u64 on lanes 0..15
    unsigned hv16 = f2bf(hv) & 0xFFFFu;
    unsigned v1 = __shfl(hv16, (lane & 15) | 16, 64);
    unsigned v2 = __shfl(hv16, (lane & 15) | 32, 64);
    unsigned v3 = __shfl(hv16, (lane & 15) | 48, 64);
    if (lane < 16) {
      unsigned long long qv = (unsigned long long)(hv16 | (v1 << 16)) |
                              ((unsigned long long)(v2 | (v3 << 16)) << 32);
      unsigned long long* dst = (unsigned long long*)
          (hrec + (size_t)(T_ - t - 1) * BH + (size_t)(wave * 16 + lane) * H_ + j0);
      __hip_atomic_store(dst, qv, __ATOMIC_RELAXED, __HIP_MEMORY_SCOPE_AGENT);
    }

    // ---- arrive: __syncthreads drains vmcnt(0) => h stores ack'd at MALL.
    //      RELAXED RMW (no wbl2). Consumers that see the counter see h. ----
    __syncthreads();
    if (tid == 0)
      __hip_atomic_fetch_add(grp, 1u, __ATOMIC_RELAXED, __HIP_MEMORY_SCOPE_AGENT);

    // ---- input GEMM for t+1 (in the arrive->release shadow) ----
    const int tn = (t + 1 < T_) ? t + 1 : t;
    f32x4 na = {0.f, 0.f, 0.f, 0.f};
    const unsigned short* a_in = a_in_base + (long long)tn * in_stride_t;
    #pragma unroll 8
    for (int kk = 0; kk < K_IN / 32; ++kk)
      na = MFMA16(*reinterpret_cast<const short8*>(&s_win[n * K_IN + ((k0 + kk * 32) ^ swz_n)]),
                  *reinterpret_cast<const short8*>(a_in + kk * 32),
                  na);
    acc = na;
  }
}

__global__ void out_head(const unsigned short* __restrict__ h2,
                         const float* __restrict__ W_out,
                         const float* __restrict__ b_out,
                         float* __restrict__ out) {
  int b = blockIdx.x;      // 64
  int lane = threadIdx.x;  // 64 (one wave)
  float s = 0.f;
  for (int k = lane; k < H_; k += 64)
    s += bf2f(h2[(size_t)b * H_ + k]) * W_out[k];
  #pragma unroll
  for (int off = 32; off; off >>= 1) s += __shfl_down(s, off, 64);
  if (lane == 0) out[b] = sigm(s + b_out[0]);
}

} // namespace

extern "C" void kernel_launch(void* const* d_in, const int* in_sizes, int n_in,
                              void* d_out, int out_size, void* d_ws, size_t ws_size,
                              hipStream_t stream) {
  const float* x    = (const float*)d_in[0];
  const float* Wih0 = (const float*)d_in[1];
  const float* Whh0 = (const float*)d_in[2];
  const float* bih0 = (const float*)d_in[3];
  const float* bhh0 = (const float*)d_in[4];
  const float* Wih1 = (const float*)d_in[5];
  const float* Whh1 = (const float*)d_in[6];
  const float* bih1 = (const float*)d_in[7];
  const float* bhh1 = (const float*)d_in[8];
  const float* Wout = (const float*)d_in[9];
  const float* bout = (const float*)d_in[10];
  float* out = (float*)d_out;

  char* ws = (char*)d_ws;
  size_t off = 0;
  auto alloc = [&](size_t bytes) -> char* {
    char* p = ws + off;
    off += (bytes + 4095) & ~(size_t)4095;   // 4KB-align every region
    return p;
  };
  const size_t REC = (size_t)(T_ + 1) * BH * 2;       // 67.2 MB (513 slabs)

  unsigned* bar        = (unsigned*)alloc(16384);     // 4096 u32: L0 at 0, L1 at 2048
  unsigned short* xb   = (unsigned short*)alloc((size_t)B_ * T_ * I_ * 2);
  unsigned short* wih0 = (unsigned short*)alloc((size_t)4 * H_ * I_ * 2);
  unsigned short* whh0 = (unsigned short*)alloc((size_t)4 * H_ * H_ * 2);
  unsigned short* wih1 = (unsigned short*)alloc((size_t)4 * H_ * H_ * 2);
  unsigned short* whh1 = (unsigned short*)alloc((size_t)4 * H_ * H_ * 2);
  unsigned short* h1   = (unsigned short*)alloc(REC);
  unsigned short* h2   = (unsigned short*)alloc(REC);

  auto cvt = [&](const float* s, unsigned short* d, int nelem) {
    int n4 = nelem / 4;
    cvt_bf16_k<<<(n4 + 255) / 256, 256, 0, stream>>>(s, d, n4);
  };
  cvt(x,    xb,   B_ * T_ * I_);
  cvt(Wih0, wih0, 4 * H_ * I_);
  cvt(Whh0, whh0, 4 * H_ * H_);
  cvt(Wih1, wih1, 4 * H_ * H_);
  cvt(Whh1, whh1, 4 * H_ * H_);
  zero_init_k<<<(BH + 255) / 256, 256, 0, stream>>>(h1, h2, bar);

  // layer 0: xb [B][T][I] bf16 (stride_t=I, stride_b=T*I), fresh reversed record
  lstm_layer<I_><<<NWG, NTHR, 0, stream>>>(
      xb, (long long)I_, (long long)T_ * I_,
      wih0, whh0, bih0, bhh0, h1, bar);

  // layer 1: input h1 slabs s=1..512 at h1+(T_-s)*BH -> base h1+(T_-1)*BH,
  // stride_t = -BH; within-slab [b][k]: stride_b = H
  lstm_layer<H_><<<NWG, NTHR, 0, stream>>>(
      h1 + (size_t)(T_ - 1) * BH, -(long long)BH, (long long)H_,
      wih1, whh1, bih1, bhh1, h2, bar + 2048);

  // final h2 = slab T at reversed offset 0
  out_head<<<B_, 64, 0, stream>>>(h2, Wout, bout, out);
}

// Round 11
// 4247.557 us; speedup vs baseline: 2.1501x; 1.7853x over previous
//
#include <hip/hip_runtime.h>
#include <hip/hip_bf16.h>

// LSTM (B=64,T=512,I=512,H=1024,O=1), 2 layers + sigmoid head.
// R11: LAYER-PIPELINED fused kernel. 514 global phases instead of 1024 steps.
//  - WGs 0..127 = layer 0, WGs 128..255 = layer 1, one shared global barrier.
//    Phase p: layer0 does step p, layer1 does step p-2 (2-phase skew).
//  - Skew=2 keeps BOTH layers' input GEMMs in the post-arrive shadow:
//    layer1's in-GEMM at phase p reads h1 slab p (written phase p-1, sealed
//    by wait(p) which this WG already passed). Race-free by construction.
//  - 8 units/WG (2 row tiles of 16 unit-major W rows). Operand swap (R10):
//    A = W from LDS, B = h/x fragments -> lane holds all 4 gates of a unit,
//    zero-shuffle elementwise. B-fragments shared across both row tiles.
//  - h protocol unchanged (R8): sc0sc1 u64 write-through stores, plain cached
//    reads of per-step FRESH slabs in REVERSE address order, RELAXED arrive
//    (no wbl2), 32 group lines x 8 WGs; ALL waves poll the 32 lines.
//  - LDS = s_win 64KB + s_whh 64KB = 128KB exactly; 1 WG/CU.

namespace {

constexpr int B_ = 64, T_ = 512, I_ = 512, H_ = 1024;
constexpr int NWG = 256, NTHR = 256;
constexpr int BH = B_ * H_;

typedef __attribute__((ext_vector_type(8))) short short8;
typedef __attribute__((ext_vector_type(4))) float f32x4;

#define MFMA16(a, b, c) __builtin_amdgcn_mfma_f32_16x16x32_bf16((a), (b), (c), 0, 0, 0)

__device__ __forceinline__ float sigm(float x)  { return 1.f / (1.f + __expf(-x)); }
__device__ __forceinline__ float tanhx(float x) { return 2.f / (1.f + __expf(-2.f * x)) - 1.f; }

__device__ __forceinline__ unsigned f2bf(float f) {
  unsigned u = __float_as_uint(f);
  unsigned rnd = 0x7FFFu + ((u >> 16) & 1u);
  return (u + rnd) >> 16;   // low 16 bits valid
}
__device__ __forceinline__ float bf2f(unsigned short s) {
  return __uint_as_float(((unsigned)s) << 16);
}

__global__ void cvt_bf16_k(const float* __restrict__ src, unsigned short* __restrict__ dst, int n4) {
  int i = blockIdx.x * 256 + threadIdx.x;
  if (i >= n4) return;
  float4 v = reinterpret_cast<const float4*>(src)[i];
  ushort4 o;
  o.x = (unsigned short)f2bf(v.x); o.y = (unsigned short)f2bf(v.y);
  o.z = (unsigned short)f2bf(v.z); o.w = (unsigned short)f2bf(v.w);
  reinterpret_cast<ushort4*>(dst)[i] = o;
}

// zero slab-0 of both records (at REVERSED position T_) and the barrier lines
__global__ void zero_init_k(unsigned short* __restrict__ h1, unsigned short* __restrict__ h2,
                            unsigned* __restrict__ bar) {
  int i = blockIdx.x * 256 + threadIdx.x;
  if (i < BH) h1[(size_t)T_ * BH + i] = 0;
  if (i < BH) h2[(size_t)T_ * BH + i] = 0;
  if (i < 1024) bar[i] = 0;             // 32 lines x 32 stride
}

// bars: 32 group lines (8 WGs each), counter g at bars[g*32]. Monotonic:
// after all arrivals of phase p each counter == 8*(p+1); wait(p): all >= 8*p.
// Records: slab s at rec + (T_-s)*BH (reverse order). Step t: read slab t,
// write slab t+1. Layer1 input for step t = h1 slab t+1.
__global__ __launch_bounds__(NTHR, 1) void lstm_fused(
    const unsigned short* __restrict__ xb,
    const unsigned short* __restrict__ wih0, const unsigned short* __restrict__ whh0,
    const float* __restrict__ bih0, const float* __restrict__ bhh0,
    const unsigned short* __restrict__ wih1, const unsigned short* __restrict__ whh1,
    const float* __restrict__ bih1, const float* __restrict__ bhh1,
    unsigned short* __restrict__ h1rec, unsigned short* __restrict__ h2rec,
    unsigned* __restrict__ bars)
{
  __shared__ unsigned short s_win[32 * 1024];   // 64 KB (layer0 uses 32x512)
  __shared__ unsigned short s_whh[32 * 1024];   // 64 KB

  const int tid   = threadIdx.x;
  const int wg    = blockIdx.x;       // 0..255
  const int layer = wg >> 7;          // 0..1
  const int lwg   = wg & 127;
  const int wave  = tid >> 6;         // 0..3 -> batch tile
  const int lane  = tid & 63;
  const int j0    = lwg * 8;          // first of 8 hidden units owned
  const int n     = lane & 15;        // W-row within tile / batch col
  const int u4    = lane >> 4;        // k-group; also unit offset in ew
  const int k0    = u4 * 8;
  const int arow  = wave * 16 + n;    // batch row for B fragments
  const int swz_n = (n & 7) << 3;

  const unsigned short* w_in = layer ? wih1 : wih0;
  const unsigned short* w_hh = layer ? whh1 : whh0;
  const float* b_i = layer ? bih1 : bih0;
  const float* b_h = layer ? bhh1 : bhh0;
  unsigned short* rec = layer ? h2rec : h1rec;
  const int K_IN = layer ? 1024 : 512;

  unsigned* grp = bars + (wg >> 3) * 32;

  // ---- stage W slices into LDS, unit-major rows r=u*4+g, XOR swizzle ----
  const int CH_IN = K_IN / 8;
  for (int c = tid; c < 32 * CH_IN; c += NTHR) {
    int r = c / CH_IN;
    int kc = (c % CH_IN) * 8;
    int grow = (r & 3) * H_ + j0 + (r >> 2);
    *reinterpret_cast<short8*>(&s_win[r * K_IN + (kc ^ ((r & 7) << 3))]) =
        *reinterpret_cast<const short8*>(&w_in[(size_t)grow * K_IN + kc]);
  }
  for (int c = tid; c < 32 * 128; c += NTHR) {
    int r = c >> 7;
    int kc = (c & 127) * 8;
    int grow = (r & 3) * H_ + j0 + (r >> 2);
    *reinterpret_cast<short8*>(&s_whh[r * H_ + (kc ^ ((r & 7) << 3))]) =
        *reinterpret_cast<const short8*>(&w_hh[(size_t)grow * H_ + kc]);
  }
  float bias0[4], bias1[4];
  #pragma unroll
  for (int g = 0; g < 4; ++g) {
    bias0[g] = b_i[g * H_ + j0 + u4]     + b_h[g * H_ + j0 + u4];
    bias1[g] = b_i[g * H_ + j0 + 4 + u4] + b_h[g * H_ + j0 + 4 + u4];
  }
  __syncthreads();

  float cst0 = 0.f, cst1 = 0.f;
  f32x4 na0 = {0.f, 0.f, 0.f, 0.f}, na1 = {0.f, 0.f, 0.f, 0.f};

  // prologue: layer0's in-acc for step 0
  if (layer == 0) {
    const unsigned short* a_in = xb + (size_t)arow * (T_ * I_) + k0;
    #pragma unroll
    for (int kk = 0; kk < 512 / 32; ++kk) {
      short8 bv = *reinterpret_cast<const short8*>(a_in + kk * 32);
      const int col = (k0 + kk * 32) ^ swz_n;
      na0 = MFMA16(*reinterpret_cast<const short8*>(&s_win[n * 512 + col]),        bv, na0);
      na1 = MFMA16(*reinterpret_cast<const short8*>(&s_win[(16 + n) * 512 + col]), bv, na1);
    }
  }

  for (int p = 0; p <= T_ + 1; ++p) {
    // ---- wait for phase p (all waves poll the 32 group lines) ----
    if (p > 0) {
      const unsigned tgt = (unsigned)p * 8u;
      for (;;) {
        unsigned v = 0xFFFFFFFFu;
        if (lane < 32)
          v = __hip_atomic_load(bars + lane * 32, __ATOMIC_RELAXED, __HIP_MEMORY_SCOPE_AGENT);
        if (__all((int)(lane >= 32 || v >= tgt))) break;
        __builtin_amdgcn_s_sleep(1);
      }
      __builtin_amdgcn_fence(__ATOMIC_ACQUIRE, "workgroup");  // ordering only, no cache ops
    }

    f32x4 acc0 = na0, acc1 = na1;
    const int t = layer ? p - 2 : p;

    if (t >= 0 && t < T_) {
      // ---- hh GEMM: B = h[slab t] (cached), A = s_whh rows (2 tiles) ----
      const unsigned short* a_h = rec + (size_t)(T_ - t) * BH + (size_t)arow * H_ + k0;
      short8 hf[32];
      #pragma unroll
      for (int kk = 0; kk < 32; ++kk)
        hf[kk] = *reinterpret_cast<const short8*>(a_h + kk * 32);
      #pragma unroll
      for (int kk = 0; kk < 32; ++kk) {
        const int col = (k0 + kk * 32) ^ swz_n;
        acc0 = MFMA16(*reinterpret_cast<const short8*>(&s_whh[n * H_ + col]),        hf[kk], acc0);
        acc1 = MFMA16(*reinterpret_cast<const short8*>(&s_whh[(16 + n) * H_ + col]), hf[kk], acc1);
      }

      // ---- elementwise (zero-shuffle): lane = (unit q*4+u4, batch arow) ----
      float gi0 = sigm(acc0[0] + bias0[0]);
      float gf0 = sigm(acc0[1] + bias0[1]);
      float gg0 = tanhx(acc0[2] + bias0[2]);
      float go0 = sigm(acc0[3] + bias0[3]);
      cst0 = gf0 * cst0 + gi0 * gg0;
      float hv0 = go0 * tanhx(cst0);

      float gi1 = sigm(acc1[0] + bias1[0]);
      float gf1 = sigm(acc1[1] + bias1[1]);
      float gg1 = tanhx(acc1[2] + bias1[2]);
      float go1 = sigm(acc1[3] + bias1[3]);
      cst1 = gf1 * cst1 + gi1 * gg1;
      float hv1 = go1 * tanhx(cst1);

      // pack 4 units per tile into u64s on lanes 0..15, bypass stores
      unsigned a16 = f2bf(hv0) & 0xFFFFu;
      unsigned b16 = f2bf(hv1) & 0xFFFFu;
      unsigned a1 = __shfl(a16, (lane & 15) | 16, 64);
      unsigned a2 = __shfl(a16, (lane & 15) | 32, 64);
      unsigned a3 = __shfl(a16, (lane & 15) | 48, 64);
      unsigned b1 = __shfl(b16, (lane & 15) | 16, 64);
      unsigned b2 = __shfl(b16, (lane & 15) | 32, 64);
      unsigned b3 = __shfl(b16, (lane & 15) | 48, 64);
      if (lane < 16) {
        unsigned long long qa = (unsigned long long)(a16 | (a1 << 16)) |
                                ((unsigned long long)(a2 | (a3 << 16)) << 32);
        unsigned long long qb = (unsigned long long)(b16 | (b1 << 16)) |
                                ((unsigned long long)(b2 | (b3 << 16)) << 32);
        unsigned long long* dst = (unsigned long long*)
            (rec + (size_t)(T_ - t - 1) * BH + (size_t)(wave * 16 + lane) * H_ + j0);
        __hip_atomic_store(dst,     qa, __ATOMIC_RELAXED, __HIP_MEMORY_SCOPE_AGENT);
        __hip_atomic_store(dst + 1, qb, __ATOMIC_RELAXED, __HIP_MEMORY_SCOPE_AGENT);
      }
    }

    // ---- arrive: __syncthreads drains vmcnt(0) => stores ack'd at MALL ----
    __syncthreads();
    if (tid == 0)
      __hip_atomic_fetch_add(grp, 1u, __ATOMIC_RELAXED, __HIP_MEMORY_SCOPE_AGENT);

    // ---- shadow: in-GEMM for this WG's next step (input sealed by wait(p)) ----
    na0 = (f32x4){0.f, 0.f, 0.f, 0.f};
    na1 = (f32x4){0.f, 0.f, 0.f, 0.f};
    const int tn = layer ? p - 1 : p + 1;
    if (tn >= 0 && tn < T_) {
      if (layer == 0) {
        const unsigned short* a_in = xb + (size_t)arow * (T_ * I_) + (size_t)tn * I_ + k0;
        #pragma unroll
        for (int kk = 0; kk < 512 / 32; ++kk) {
          short8 bv = *reinterpret_cast<const short8*>(a_in + kk * 32);
          const int col = (k0 + kk * 32) ^ swz_n;
          na0 = MFMA16(*reinterpret_cast<const short8*>(&s_win[n * 512 + col]),        bv, na0);
          na1 = MFMA16(*reinterpret_cast<const short8*>(&s_win[(16 + n) * 512 + col]), bv, na1);
        }
      } else {
        // input = h1 slab tn+1, written phase tn (= p-1), sealed by wait(p)
        const unsigned short* a_in = h1rec + (size_t)(T_ - 1 - tn) * BH + (size_t)arow * H_ + k0;
        #pragma unroll
        for (int kk = 0; kk < 1024 / 32; ++kk) {
          short8 bv = *reinterpret_cast<const short8*>(a_in + kk * 32);
          const int col = (k0 + kk * 32) ^ swz_n;
          na0 = MFMA16(*reinterpret_cast<const short8*>(&s_win[n * 1024 + col]),        bv, na0);
          na1 = MFMA16(*reinterpret_cast<const short8*>(&s_win[(16 + n) * 1024 + col]), bv, na1);
        }
      }
    }
  }
}

__global__ void out_head(const unsigned short* __restrict__ h2,
                         const float* __restrict__ W_out,
                         const float* __restrict__ b_out,
                         float* __restrict__ out) {
  int b = blockIdx.x;      // 64
  int lane = threadIdx.x;  // 64 (one wave)
  float s = 0.f;
  for (int k = lane; k < H_; k += 64)
    s += bf2f(h2[(size_t)b * H_ + k]) * W_out[k];
  #pragma unroll
  for (int off = 32; off; off >>= 1) s += __shfl_down(s, off, 64);
  if (lane == 0) out[b] = sigm(s + b_out[0]);
}

} // namespace

extern "C" void kernel_launch(void* const* d_in, const int* in_sizes, int n_in,
                              void* d_out, int out_size, void* d_ws, size_t ws_size,
                              hipStream_t stream) {
  const float* x    = (const float*)d_in[0];
  const float* Wih0 = (const float*)d_in[1];
  const float* Whh0 = (const float*)d_in[2];
  const float* bih0 = (const float*)d_in[3];
  const float* bhh0 = (const float*)d_in[4];
  const float* Wih1 = (const float*)d_in[5];
  const float* Whh1 = (const float*)d_in[6];
  const float* bih1 = (const float*)d_in[7];
  const float* bhh1 = (const float*)d_in[8];
  const float* Wout = (const float*)d_in[9];
  const float* bout = (const float*)d_in[10];
  float* out = (float*)d_out;

  char* ws = (char*)d_ws;
  size_t off = 0;
  auto alloc = [&](size_t bytes) -> char* {
    char* p = ws + off;
    off += (bytes + 4095) & ~(size_t)4095;   // 4KB-align every region
    return p;
  };
  const size_t REC = (size_t)(T_ + 1) * BH * 2;       // 67.2 MB (513 slabs)

  unsigned* bar        = (unsigned*)alloc(4096);      // 1024 u32 (32 lines)
  unsigned short* xb   = (unsigned short*)alloc((size_t)B_ * T_ * I_ * 2);
  unsigned short* wih0 = (unsigned short*)alloc((size_t)4 * H_ * I_ * 2);
  unsigned short* whh0 = (unsigned short*)alloc((size_t)4 * H_ * H_ * 2);
  unsigned short* wih1 = (unsigned short*)alloc((size_t)4 * H_ * H_ * 2);
  unsigned short* whh1 = (unsigned short*)alloc((size_t)4 * H_ * H_ * 2);
  unsigned short* h1   = (unsigned short*)alloc(REC);
  unsigned short* h2   = (unsigned short*)alloc(REC);

  auto cvt = [&](const float* s, unsigned short* d, int nelem) {
    int n4 = nelem / 4;
    cvt_bf16_k<<<(n4 + 255) / 256, 256, 0, stream>>>(s, d, n4);
  };
  cvt(x,    xb,   B_ * T_ * I_);
  cvt(Wih0, wih0, 4 * H_ * I_);
  cvt(Whh0, whh0, 4 * H_ * H_);
  cvt(Wih1, wih1, 4 * H_ * H_);
  cvt(Whh1, whh1, 4 * H_ * H_);
  zero_init_k<<<(BH + 255) / 256, 256, 0, stream>>>(h1, h2, bar);

  lstm_fused<<<NWG, NTHR, 0, stream>>>(
      xb, wih0, whh0, bih0, bhh0, wih1, whh1, bih1, bhh1, h1, h2, bar);

  // final h2 = layer1 step 511 output = slab 512 -> reversed offset 0
  out_head<<<B_, 64, 0, stream>>>(h2, Wout, bout, out);
}